// Round 1
// baseline (74.939 us; speedup 1.0000x reference)
//
#include <hip/hip_runtime.h>

// RNNAdder: out[row] = digits of (a[row] + b[row]) in base 10, MSB-first,
// with a leading final-carry column. Shapes: a,b (B,2048) f32 digits 0..9;
// out (B,2049) int32.
//
// One block per row, 256 threads, 8 digits/thread. Carry propagation via
// generate/propagate monoid scan (Kogge-Stone in LDS).

#define NDIG 2048
#define TPB 256
#define DPT 8  // digits per thread

__global__ __launch_bounds__(TPB) void rnn_adder_kernel(
    const float* __restrict__ A, const float* __restrict__ B,
    int* __restrict__ out) {
  const int row = blockIdx.x;
  const int t = threadIdx.x;
  // Thread t owns original columns [base, base+8); t=0 is the rightmost
  // (least significant) chunk so carry flows t=0 -> t=255.
  const int base = NDIG - (t + 1) * DPT;

  const float4* A4 = reinterpret_cast<const float4*>(A + (size_t)row * NDIG + base);
  const float4* B4 = reinterpret_cast<const float4*>(B + (size_t)row * NDIG + base);
  float4 a0 = A4[0], a1 = A4[1];
  float4 b0 = B4[0], b1 = B4[1];

  int s[DPT];
  s[0] = (int)a0.x + (int)b0.x;
  s[1] = (int)a0.y + (int)b0.y;
  s[2] = (int)a0.z + (int)b0.z;
  s[3] = (int)a0.w + (int)b0.w;
  s[4] = (int)a1.x + (int)b1.x;
  s[5] = (int)a1.y + (int)b1.y;
  s[6] = (int)a1.z + (int)b1.z;
  s[7] = (int)a1.w + (int)b1.w;

  // Local carry-transfer function: c_out as function of c_in, evaluated at 0
  // and 1. Within the chunk, s[7] is the least significant digit.
  int c0 = 0, c1 = 1;
#pragma unroll
  for (int k = DPT - 1; k >= 0; --k) {
    c0 = (s[k] + c0) >= 10;
    c1 = (s[k] + c1) >= 10;
  }

  // Pack f(c) = (f >> c) & 1. Identity = 0b10 (f(0)=0, f(1)=1).
  __shared__ int sc[TPB];
  int cur = c0 | (c1 << 1);
  sc[t] = cur;
  __syncthreads();

  // Inclusive Kogge-Stone scan: after the loop sc[t] = F_t o ... o F_0.
#pragma unroll
  for (int off = 1; off < TPB; off <<= 1) {
    int prev = (t >= off) ? sc[t - off] : 2;  // identity for t < off
    __syncthreads();
    // cur = cur o prev (apply prev first): new(c) = cur(prev(c))
    int p0 = prev & 1, p1 = (prev >> 1) & 1;
    cur = ((cur >> p0) & 1) | (((cur >> p1) & 1) << 1);
    sc[t] = cur;
    __syncthreads();
  }

  // Incoming carry for thread t = (F_{t-1} o ... o F_0)(0).
  int cin = (t == 0) ? 0 : (sc[t - 1] & 1);

  // Finalize digits, LSB of chunk first.
  int c = cin;
  int d[DPT];
#pragma unroll
  for (int k = DPT - 1; k >= 0; --k) {
    int v = s[k] + c;
    c = (v >= 10);
    d[k] = v - 10 * c;
  }

  int* orow = out + (size_t)row * (NDIG + 1);
#pragma unroll
  for (int k = 0; k < DPT; ++k) orow[1 + base + k] = d[k];
  if (t == TPB - 1) orow[0] = c;  // carry out of the most significant digit
}

extern "C" void kernel_launch(void* const* d_in, const int* in_sizes, int n_in,
                              void* d_out, int out_size, void* d_ws, size_t ws_size,
                              hipStream_t stream) {
  const float* A = (const float*)d_in[0];
  const float* B = (const float*)d_in[1];
  int* out = (int*)d_out;
  const int rows = in_sizes[0] / NDIG;
  rnn_adder_kernel<<<rows, TPB, 0, stream>>>(A, B, out);
}